// Round 7
// baseline (357.634 us; speedup 1.0000x reference)
//
#include <hip/hip_runtime.h>

#define NN 2000
#define TT 12

// workspace layout (in floats)
#define XOFF    0          // x buffer f16: (B,N,T,C) = 16*2000*12*32 f16 = 6,144,000 floats
#define SKOFF   6144000    // skip: (B,N,C) = 1,024,000 floats
#define CHOFF   7168000    // ch: N*4
#define CMOFF   7176000    // char_m: N*4
#define STOFF   7184000    // stats: 96
#define WGOFF   7185000    // per-layer A-frags f16: 2000*20*512 f16 = 10,240,000 floats
#define RWGOFF  17425000   // per-layer rw frags f16: 2000*2*512 f16 = 1,024,000 floats
#define BIASOFF 18449000   // per-layer biases f32: 2000*96 = 192,000 floats
// total ~18,641,000 floats = 74.6 MB

typedef __fp16 f16x8 __attribute__((ext_vector_type(8)));
typedef float  f32x4 __attribute__((ext_vector_type(4)));

union U32H2 { unsigned int u; __fp16 h[2]; };
__device__ __forceinline__ unsigned int pkh(float a, float b){
  U32H2 v; v.h[0] = (__fp16)a; v.h[1] = (__fp16)b; return v.u;
}
__device__ __forceinline__ float fsig(float x){ return 1.0f/(1.0f + __expf(-x)); }
__device__ __forceinline__ float ftanh(float x){ return 1.0f - 2.0f/(1.0f + __expf(2.0f*x)); }

__global__ void k_init(float* stats){
  int t = threadIdx.x;
  if (t < 96) stats[t] = 0.0f;
}

__global__ void k_charm(const float* __restrict__ input,
                        const float* __restrict__ charac,
                        float* __restrict__ cm)
{
  int idx = blockIdx.x*256 + threadIdx.x;
  if (idx >= NN*4) return;
  int n = idx >> 2, r = idx & 3;
  int mv = (int)input[TT];
  int m = ((mv % 12) + 12) % 12;
  int m0 = (m + 11) % 12, m2 = (m + 1) % 12;
  const float* base = charac + n*48;
  cm[idx] = (base[m0*4+r] + base[m*4+r] + base[m2*4+r]) * (1.0f/3.0f);
}

__global__ __launch_bounds__(256) void k_ch(const float* __restrict__ adj,
                                            const float* __restrict__ cm,
                                            float* __restrict__ ch)
{
  __shared__ float red[256][4];
  int n = blockIdx.x, t = threadIdx.x;
  float s0=0.f, s1=0.f, s2=0.f, s3=0.f;
  const float* arow = adj + (size_t)n*NN;
  for (int c = t; c < NN; c += 256){
    float a = arow[c];
    float4 v = *reinterpret_cast<const float4*>(cm + c*4);
    s0 = fmaf(a, v.x, s0); s1 = fmaf(a, v.y, s1);
    s2 = fmaf(a, v.z, s2); s3 = fmaf(a, v.w, s3);
  }
  red[t][0]=s0; red[t][1]=s1; red[t][2]=s2; red[t][3]=s3;
  __syncthreads();
  for (int off = 128; off > 0; off >>= 1){
    if (t < off){
      red[t][0]+=red[t+off][0]; red[t][1]+=red[t+off][1];
      red[t][2]+=red[t+off][2]; red[t][3]+=red[t+off][3];
    }
    __syncthreads();
  }
  if (t < 4) ch[n*4+t] = red[0][t];
}

// ---------------------------------------------------------------------------
// k_wgen: per (layer), 8 nodes per block. Emits per-node weights in MFMA
// fragment order:
//   WG[n][sid][r16][c] f16, sid: h=0: fg*3+jj (6 slices); h=1: 6+fg*7+jj (14)
//   RWG[n][h][r16][c] f16 ; BIAS[n][which(f,g,r)][oc] f32
// W reads coalesced (lane = consecutive col); writes scattered f16 -> L2.
// ---------------------------------------------------------------------------
__global__ __launch_bounds__(256) void k_wgen(
    int layer, const float* __restrict__ ch,
    const float* __restrict__ Wcw, const float* __restrict__ bcw,
    const float* __restrict__ Wcb, const float* __restrict__ bcb,
    const float* __restrict__ Wgw, const float* __restrict__ bgw,
    const float* __restrict__ Wgb, const float* __restrict__ bgb,
    const float* __restrict__ Wrw, const float* __restrict__ brw,
    const float* __restrict__ Wrb, const float* __restrict__ brb,
    __fp16* __restrict__ WG, __fp16* __restrict__ RWG, float* __restrict__ BIAS)
{
  __shared__ float chs[32];      // 8 nodes x 4
  __shared__ float chbs[32];     // [gi(2)][s(4)][r(4)]
  const int tid = threadIdx.x;
  const int n0 = blockIdx.x * 8;
  if (tid < 32) chs[tid] = ch[n0*4 + tid];
  else if (tid < 64){
    int q = tid - 32; int gi = q >> 4, s = (q >> 2) & 3, r = q & 3;
    chbs[gi*16 + s*4 + r] = ch[(s*500 + (n0>>2) + gi)*4 + r];
  }
  __syncthreads();

  // conv + gate weights
  for (int i = tid; i < 4608; i += 256){
    int o = i/576, rem = i - o*576, c = rem/18, u = rem - c*18;
    int s = (u>=2)+(u>=5)+(u>=11);
    int lo = (s==0)?0:((s==1)?2:((s==2)?5:11));
    int jj = u - lo;
    int h = (s >= 2);
    int row = ((s&1)<<3) + o;
    int sidf = h ? (6+jj) : jj;
    int sidg = h ? (13+jj) : (3+jj);
    int col = layer*4608 + i;
    float cw0=Wcw[col], cw1=Wcw[13824+col], cw2=Wcw[27648+col], cw3=Wcw[41472+col], cb=bcw[col];
    float gw0=Wgw[col], gw1=Wgw[13824+col], gw2=Wgw[27648+col], gw3=Wgw[41472+col], gb=bgw[col];
    int dbf = sidf*512 + row*32 + c;
    int dbg = sidg*512 + row*32 + c;
#pragma unroll
    for (int g = 0; g < 8; ++g){
      const float* cg = &chs[g*4];
      float wf = fmaf(cg[0],cw0, fmaf(cg[1],cw1, fmaf(cg[2],cw2, fmaf(cg[3],cw3, cb))));
      float wg = fmaf(cg[0],gw0, fmaf(cg[1],gw1, fmaf(cg[2],gw2, fmaf(cg[3],gw3, gb))));
      WG[(size_t)(n0+g)*10240 + dbf] = (__fp16)wf;
      WG[(size_t)(n0+g)*10240 + dbg] = (__fp16)wg;
    }
  }
  // zero the padding slices: (sid 2,5 rows 0-7) and (sid 12,19 rows 0-7)
  {
    unsigned int* WU = reinterpret_cast<unsigned int*>(WG);
    for (int z = tid; z < 4096; z += 256){
      int g = z >> 9, rem = z & 511;
      int qs = rem >> 7;
      int sid = (qs==0)?2:((qs==1)?5:((qs==2)?12:19));
      int r = (rem >> 4) & 7, cp = rem & 15;
      WU[(size_t)(n0+g)*5120 + sid*256 + r*16 + cp] = 0u;
    }
  }
  // residual weights
  for (int i = tid; i < 1024; i += 256){
    int oc = i >> 5, c = i & 31;
    int col = layer*1024 + i;
    float r0=Wrw[col], r1=Wrw[3072+col], r2=Wrw[6144+col], r3=Wrw[9216+col], rb=brw[col];
    int dst = (oc>>4)*512 + (oc&15)*32 + c;
#pragma unroll
    for (int g = 0; g < 8; ++g){
      const float* cg = &chs[g*4];
      float v = fmaf(cg[0],r0, fmaf(cg[1],r1, fmaf(cg[2],r2, fmaf(cg[3],r3, rb))));
      RWG[(size_t)(n0+g)*1024 + dst] = (__fp16)v;
    }
  }
  // biases (f, g use the reshuffle; r plain)
  for (int idx = tid; idx < 768; idx += 256){
    int g = idx / 96, r96 = idx - g*96;
    int which = r96 >> 5, oc = r96 & 31;
    int n = n0 + g;
    float out;
    if (which < 2){
      int s = oc >> 3;
      int v = ((n&3)<<3) + (oc&7);
      int col = layer*32 + v;
      const float* cb4 = &chbs[(g>>2)*16 + s*4];
      const float* Wb = which ? Wgb : Wcb;
      const float* bb = which ? bgb : bcb;
      out = fmaf(cb4[0],Wb[col], fmaf(cb4[1],Wb[96+col],
            fmaf(cb4[2],Wb[192+col], fmaf(cb4[3],Wb[288+col], bb[col]))));
    } else {
      int col = layer*32 + oc;
      const float* cg = &chs[g*4];
      out = fmaf(cg[0],Wrb[col], fmaf(cg[1],Wrb[96+col],
            fmaf(cg[2],Wrb[192+col], fmaf(cg[3],Wrb[288+col], brb[col]))));
    }
    BIAS[(size_t)n*96 + which*32 + oc] = out;
  }
}

// ---------------------------------------------------------------------------
// k_conv: per node. A-fragments streamed from WG/RWG (global, L3) straight
// into registers; LDS only for x / gated tiles. xbuf is f16 [b][n][t][c].
// ---------------------------------------------------------------------------
__global__ __launch_bounds__(256,3) void k_conv(
    int layer,
    __fp16* __restrict__ xbuf, float* __restrict__ skipbuf,
    float* stats, const float* __restrict__ input,
    const __fp16* __restrict__ WG, const __fp16* __restrict__ RWG,
    const float* __restrict__ BIAS,
    const float* __restrict__ start_w, const float* __restrict__ start_b,
    const float* __restrict__ sk0w, const float* __restrict__ sk0b,
    const float* __restrict__ skw_all, const float* __restrict__ skb_all,
    const float* __restrict__ lnw_all, const float* __restrict__ lnb_all)
{
  __shared__ __fp16 xh[7680];        // [t][b][c] stride 40
  __shared__ __fp16 gh[7680];        // [t][b][c] stride 40
  __shared__ float skred[1024];
  __shared__ float wred[128];
  __shared__ float ubuf[1280];
  __shared__ float skwv[384];
  __shared__ float skbv[32];
  __shared__ float muv[16], rsv[16];

  const int tid = threadIdx.x;
  const int n = blockIdx.x;

  float* swv  = ubuf;        // 64   (layer 0)
  float* sbv  = ubuf + 64;   // 32
  float* s0wv = ubuf + 96;   // 768
  float* s0bv = ubuf + 864;  // 32
  float* xin  = ubuf + 896;  // 384 = 16 b x 24
  float* lnwv = ubuf;        // 384  (layer > 0), [c*12+t]
  float* lnbv = ubuf + 384;  // 384

  const int lane = tid & 63, w = tid >> 6;
  const int h = w & 1, nh = w >> 1;
  const int r16 = lane & 15, hi4 = lane >> 4;
  const int c0 = hi4*8;
  const int oc0 = h*16 + hi4*4;
  const int njj = h ? 7 : 3;

  // ---- early global fragment loads (independent of LDS) ----
  const __fp16* WGn = WG + (size_t)n*10240;
  f16x8 aF[7], aG[7];
#pragma unroll 7
  for (int jj = 0; jj < 7; ++jj) if (jj < njj){
    aF[jj] = *reinterpret_cast<const f16x8*>(WGn + (h?(6+jj):jj)*512 + r16*32 + c0);
    aG[jj] = *reinterpret_cast<const f16x8*>(WGn + (h?(13+jj):(3+jj))*512 + r16*32 + c0);
  }
  f16x8 ar = *reinterpret_cast<const f16x8*>(RWG + (size_t)n*1024 + h*512 + r16*32 + c0);
  float4 fq = *reinterpret_cast<const float4*>(BIAS + (size_t)n*96 + oc0);
  float4 gq = *reinterpret_cast<const float4*>(BIAS + (size_t)n*96 + 32 + oc0);
  float4 rq = *reinterpret_cast<const float4*>(BIAS + (size_t)n*96 + 64 + oc0);
  float fb4[4] = {fq.x, fq.y, fq.z, fq.w};
  float gb4[4] = {gq.x, gq.y, gq.z, gq.w};
  float rb4[4] = {rq.x, rq.y, rq.z, rq.w};

  // ---- constants ----
  for (int i = tid; i < 32; i += 256) skbv[i] = skb_all[layer*32+i];
  for (int i = tid; i < 384; i += 256) skwv[i] = skw_all[layer*384+i];
  if (layer == 0){
    for (int i = tid; i < 64; i += 256) swv[i] = start_w[i];
    for (int i = tid; i < 32; i += 256){ sbv[i] = start_b[i]; s0bv[i] = sk0b[i]; }
    for (int i = tid; i < 768; i += 256) s0wv[i] = sk0w[i];
    for (int i = tid; i < 384; i += 256){
      int bb = i/24, r = i%24, d = r/12, t = r%12;
      xin[i] = input[(((size_t)bb*2 + d)*NN + n)*13 + t];
    }
  } else {
    for (int i = tid; i < 384; i += 256){
      int c = i/12, t = i%12;
      size_t o = (((size_t)(layer-1)*32 + c)*NN + n)*12 + t;
      lnwv[i] = lnw_all[o]; lnbv[i] = lnb_all[o];
    }
    if (tid < 16){
      float S1 = stats[(layer-1)*32 + tid];
      float S2 = stats[(layer-1)*32 + 16 + tid];
      const float M = 768000.0f;
      float mu = S1 / M;
      muv[tid] = mu;
      rsv[tid] = rsqrtf(S2/M - mu*mu + 1e-5f);
    }
  }
  __syncthreads();

  // ---- stage xh[t][b][c] ----
  if (tid < 192){
    int b = tid / 12, t = tid - (tid/12)*12;
    float xv[32];
    if (layer == 0){
      float xa = xin[b*24 + t], xb2 = xin[b*24 + 12 + t];
#pragma unroll
      for (int c = 0; c < 32; ++c)
        xv[c] = fmaf(swv[c*2], xa, fmaf(swv[c*2+1], xb2, sbv[c]));
    } else {
      const uint4* src = reinterpret_cast<const uint4*>(
          xbuf + (((size_t)b*NN + n)*12 + t)*32);
      uint4 u0 = src[0], u1 = src[1], u2 = src[2], u3 = src[3];
      unsigned int uu[16] = {u0.x,u0.y,u0.z,u0.w, u1.x,u1.y,u1.z,u1.w,
                             u2.x,u2.y,u2.z,u2.w, u3.x,u3.y,u3.z,u3.w};
      float mu = muv[b], rs = rsv[b];
#pragma unroll
      for (int j = 0; j < 16; ++j){
        U32H2 vv; vv.u = uu[j];
        int c = j*2;
        xv[c]   = fmaf(((float)vv.h[0]-mu)*rs, lnwv[c*12+t],     lnbv[c*12+t]);
        xv[c+1] = fmaf(((float)vv.h[1]-mu)*rs, lnwv[(c+1)*12+t], lnbv[(c+1)*12+t]);
      }
    }
    unsigned int pk[16];
#pragma unroll
    for (int j = 0; j < 16; ++j) pk[j] = pkh(xv[2*j], xv[2*j+1]);
    uint4* dst = reinterpret_cast<uint4*>(&xh[(t*16 + b)*40]);
    dst[0] = make_uint4(pk[0], pk[1], pk[2], pk[3]);
    dst[1] = make_uint4(pk[4], pk[5], pk[6], pk[7]);
    dst[2] = make_uint4(pk[8], pk[9], pk[10], pk[11]);
    dst[3] = make_uint4(pk[12],pk[13],pk[14],pk[15]);
  }
  __syncthreads();

  // ---- phase 2: MFMA conv + activation + gated store + skip partials ----
  float sv[4] = {0.f, 0.f, 0.f, 0.f};
#pragma unroll
  for (int q = 0; q < 6; ++q){
    int nt = nh*6 + q;
    f32x4 accf = {0.f,0.f,0.f,0.f}, accg = {0.f,0.f,0.f,0.f};
#pragma unroll 7
    for (int jj = 0; jj < 7; ++jj) if (jj < njj){
      int tp = nt + jj; if (tp >= 12) tp -= 12;
      f16x8 bf = *reinterpret_cast<const f16x8*>(&xh[(tp*16 + r16)*40 + c0]);
      accf = __builtin_amdgcn_mfma_f32_16x16x32_f16(aF[jj], bf, accf, 0, 0, 0);
      accg = __builtin_amdgcn_mfma_f32_16x16x32_f16(aG[jj], bf, accg, 0, 0, 0);
    }
    float gv4[4];
#pragma unroll
    for (int i2 = 0; i2 < 4; ++i2){
      float fv = ftanh(accf[i2] + fb4[i2]);
      float gg = fsig(accg[i2] + gb4[i2]);
      gv4[i2] = fv * gg;
      sv[i2] = fmaf(gv4[i2], skwv[(oc0+i2)*12 + nt], sv[i2]);
    }
    *reinterpret_cast<uint2*>(&gh[(nt*16 + r16)*40 + oc0]) =
        make_uint2(pkh(gv4[0], gv4[1]), pkh(gv4[2], gv4[3]));
  }
#pragma unroll
  for (int i2 = 0; i2 < 4; ++i2)
    skred[((oc0+i2)*16 + r16)*2 + nh] = sv[i2];
  __syncthreads();

  // ---- phase 3: skip finalize + residual GEMM + epilogue + stats ----
  for (int e = tid; e < 512; e += 256){
    int b = e >> 5, oc = e & 31;
    float sk = skred[(oc*16+b)*2] + skred[(oc*16+b)*2+1] + skbv[oc];
    size_t so = ((size_t)b*NN + n)*32 + oc;
    if (layer == 0){
      float s0 = s0bv[oc];
#pragma unroll
      for (int r = 0; r < 24; ++r) s0 = fmaf(xin[b*24+r], s0wv[oc*24+r], s0);
      skipbuf[so] = sk + s0;
    } else {
      skipbuf[so] += sk;
    }
  }
  {
    float s1 = 0.f, s2 = 0.f;
#pragma unroll
    for (int q = 0; q < 6; ++q){
      int nt = nh*6 + q;
      f16x8 bg = *reinterpret_cast<const f16x8*>(&gh[(nt*16 + r16)*40 + c0]);
      f32x4 z = {0.f,0.f,0.f,0.f};
      f32x4 acc = __builtin_amdgcn_mfma_f32_16x16x32_f16(ar, bg, z, 0, 0, 0);
      uint2 xu = *reinterpret_cast<const uint2*>(&xh[(nt*16 + r16)*40 + oc0]);
      U32H2 ua, ub; ua.u = xu.x; ub.u = xu.y;
      float o0 = acc[0] + rb4[0] + (float)ua.h[0];
      float o1 = acc[1] + rb4[1] + (float)ua.h[1];
      float o2 = acc[2] + rb4[2] + (float)ub.h[0];
      float o3 = acc[3] + rb4[3] + (float)ub.h[1];
      *reinterpret_cast<uint2*>(
          xbuf + (((size_t)r16*NN + n)*12 + nt)*32 + oc0) =
          make_uint2(pkh(o0, o1), pkh(o2, o3));
      s1 += o0 + o1 + o2 + o3;
      s2 = fmaf(o0,o0, fmaf(o1,o1, fmaf(o2,o2, fmaf(o3,o3, s2))));
    }
    s1 += __shfl_xor(s1, 16); s2 += __shfl_xor(s2, 16);
    s1 += __shfl_xor(s1, 32); s2 += __shfl_xor(s2, 32);
    if (hi4 == 0){
      wred[(w*16 + r16)*2]     = s1;
      wred[(w*16 + r16)*2 + 1] = s2;
    }
  }
  __syncthreads();
  if (tid < 16){
    float a1 = 0.f, a2 = 0.f;
    for (int w2 = 0; w2 < 4; ++w2){
      a1 += wred[(w2*16 + tid)*2];
      a2 += wred[(w2*16 + tid)*2 + 1];
    }
    atomicAdd(&stats[layer*32 + tid], a1);
    atomicAdd(&stats[layer*32 + 16 + tid], a2);
  }
}

__global__ __launch_bounds__(256) void k_final(
    const __fp16* __restrict__ xbuf, const float* __restrict__ skipbuf,
    const float* __restrict__ stats,
    const float* __restrict__ lnw_all, const float* __restrict__ lnb_all,
    const float* __restrict__ skEw, const float* __restrict__ skEb,
    const float* __restrict__ e1w, const float* __restrict__ e1b,
    const float* __restrict__ e2w, const float* __restrict__ e2b,
    float* __restrict__ out)
{
  __shared__ float lnw[384], lnb[384], skE[384];
  __shared__ float e1[32*33];
  __shared__ float e1bv[32], e2v[32], skEbv[32];
  __shared__ float muv[16], rsv[16];
  __shared__ float skf[8][33];
  const int tid = threadIdx.x, n = blockIdx.x;
  for (int i = tid; i < 384; i += 256){
    int c = i/12, t = i%12;
    size_t o = (((size_t)2*32 + c)*NN + n)*12 + t;
    lnw[i] = lnw_all[o]; lnb[i] = lnb_all[o];
    skE[i] = skEw[i];
  }
  for (int i = tid; i < 1024; i += 256) e1[(i>>5)*33 + (i&31)] = e1w[i];
  if (tid < 32){ e1bv[tid] = e1b[tid]; e2v[tid] = e2w[tid]; skEbv[tid] = skEb[tid]; }
  if (tid < 16){
    float S1 = stats[64+tid], S2 = stats[80+tid];
    const float M = 768000.0f;
    float mu = S1/M; muv[tid] = mu;
    rsv[tid] = rsqrtf(S2/M - mu*mu + 1e-5f);
  }
  __syncthreads();
  const float e2b0 = e2b[0];
  for (int bo = 0; bo < 2; ++bo){
    const int g = tid >> 5, c = tid & 31, b = bo*8 + g;
    float xr[12];
#pragma unroll
    for (int t = 0; t < 12; ++t)
      xr[t] = (float)xbuf[(((size_t)b*NN + n)*12 + t)*32 + c];
    const float mu = muv[b], rs = rsv[b];
    float se = 0.0f;
#pragma unroll
    for (int t = 0; t < 12; ++t){
      float xv = fmaf((xr[t]-mu)*rs, lnw[c*12+t], lnb[c*12+t]);
      se = fmaf(xv, skE[c*12+t], se);
    }
    float sk = se + skEbv[c] + skipbuf[((size_t)b*NN+n)*32 + c];
    skf[g][c] = fmaxf(sk, 0.0f);
    __syncthreads();
    float acc = e1bv[c];
#pragma unroll
    for (int cc = 0; cc < 32; ++cc) acc = fmaf(skf[g][cc], e1[c*33+cc], acc);
    float y1 = fmaxf(acc, 0.0f);
    float part = y1 * e2v[c];
#pragma unroll
    for (int off = 16; off > 0; off >>= 1) part += __shfl_down(part, off, 32);
    if (c == 0) out[(size_t)b*NN + n] = part + e2b0;
    __syncthreads();
  }
}

extern "C" void kernel_launch(void* const* d_in, const int* in_sizes, int n_in,
                              void* d_out, int out_size, void* d_ws, size_t ws_size,
                              hipStream_t stream)
{
  (void)in_sizes; (void)n_in; (void)out_size; (void)ws_size;
  const float* input   = (const float*)d_in[0];
  const float* adj     = (const float*)d_in[1];
  const float* charac  = (const float*)d_in[2];
  const float* Wcw     = (const float*)d_in[3];
  const float* bcw     = (const float*)d_in[4];
  const float* Wcb     = (const float*)d_in[5];
  const float* bcb     = (const float*)d_in[6];
  const float* Wgw     = (const float*)d_in[7];
  const float* bgw     = (const float*)d_in[8];
  const float* Wgb     = (const float*)d_in[9];
  const float* bgb     = (const float*)d_in[10];
  const float* Wrw     = (const float*)d_in[11];
  const float* brw     = (const float*)d_in[12];
  const float* Wrb     = (const float*)d_in[13];
  const float* brb     = (const float*)d_in[14];
  const float* start_w = (const float*)d_in[15];
  const float* start_b = (const float*)d_in[16];
  const float* sk0w    = (const float*)d_in[17];
  const float* sk0b    = (const float*)d_in[18];
  const float* skw     = (const float*)d_in[19];
  const float* skb     = (const float*)d_in[20];
  const float* skEw    = (const float*)d_in[21];
  const float* skEb    = (const float*)d_in[22];
  const float* lnw     = (const float*)d_in[23];
  const float* lnb     = (const float*)d_in[24];
  const float* e1w     = (const float*)d_in[25];
  const float* e1b     = (const float*)d_in[26];
  const float* e2w     = (const float*)d_in[27];
  const float* e2b     = (const float*)d_in[28];

  float* ws     = (float*)d_ws;
  __fp16* xbuf  = (__fp16*)(ws + XOFF);
  float* skipb  = ws + SKOFF;
  float* chbuf  = ws + CHOFF;
  float* cmbuf  = ws + CMOFF;
  float* stats  = ws + STOFF;
  __fp16* WG    = (__fp16*)(ws + WGOFF);
  __fp16* RWG   = (__fp16*)(ws + RWGOFF);
  float* BIAS   = ws + BIASOFF;
  float* outp   = (float*)d_out;

  k_init<<<1, 128, 0, stream>>>(stats);
  k_charm<<<32, 256, 0, stream>>>(input, charac, cmbuf);
  k_ch<<<NN, 256, 0, stream>>>(adj, cmbuf, chbuf);
  for (int layer = 0; layer < 3; ++layer){
    k_wgen<<<NN/8, 256, 0, stream>>>(layer, chbuf,
        Wcw, bcw, Wcb, bcb, Wgw, bgw, Wgb, bgb, Wrw, brw, Wrb, brb,
        WG, RWG, BIAS);
    k_conv<<<NN, 256, 0, stream>>>(layer, xbuf, skipb, stats, input,
        WG, RWG, BIAS,
        start_w, start_b, sk0w, sk0b, skw, skb, lnw, lnb);
  }
  k_final<<<NN, 256, 0, stream>>>(xbuf, skipb, stats, lnw, lnb,
      skEw, skEb, e1w, e1b, e2w, e2b, outp);
}

// Round 9
// 226.782 us; speedup vs baseline: 1.5770x; 1.5770x over previous
//
#include <hip/hip_runtime.h>

#define NN 2000
#define TT 12

// workspace layout (in floats)
#define XOFF    0          // x buffer f16: (B,N,T,C) = 16*2000*12*32 f16 = 6,144,000 floats
#define SKOFF   6144000    // skip: (B,N,C) f32
#define CHOFF   7168000    // ch: N*4
#define CMOFF   7176000    // char_m: N*4
#define STOFF   7184000    // stats: 96
#define PARTOFF 7184100    // per-node stat partials: 2000*32
#define PKWOFF  7248100    // packed conv+gate rank weights f32: 13824*8 = 110592
#define PKBOFF  7358692    // packed conv+gate rank biases f32: 13824*2 = 27648
#define PKROFF  7386340    // packed residual rank weights f32: 3072*8 = 24576
// total ~7,410,916 floats = 29.6 MB

typedef __fp16 f16x8 __attribute__((ext_vector_type(8)));
typedef float  f32x4 __attribute__((ext_vector_type(4)));

union U32H2 { unsigned int u; __fp16 h[2]; };
__device__ __forceinline__ unsigned int pkh(float a, float b){
  U32H2 v; v.h[0] = (__fp16)a; v.h[1] = (__fp16)b; return v.u;
}
__device__ __forceinline__ float fsig(float x){ return 1.0f/(1.0f + __expf(-x)); }
__device__ __forceinline__ float ftanh(float x){ return 1.0f - 2.0f/(1.0f + __expf(2.0f*x)); }

__global__ void k_charm(const float* __restrict__ input,
                        const float* __restrict__ charac,
                        float* __restrict__ cm)
{
  int idx = blockIdx.x*256 + threadIdx.x;
  if (idx >= NN*4) return;
  int n = idx >> 2, r = idx & 3;
  int mv = (int)input[TT];
  int m = ((mv % 12) + 12) % 12;
  int m0 = (m + 11) % 12, m2 = (m + 1) % 12;
  const float* base = charac + n*48;
  cm[idx] = (base[m0*4+r] + base[m*4+r] + base[m2*4+r]) * (1.0f/3.0f);
}

__global__ __launch_bounds__(256) void k_ch(const float* __restrict__ adj,
                                            const float* __restrict__ cm,
                                            float* __restrict__ ch)
{
  __shared__ float red[256][4];
  int n = blockIdx.x, t = threadIdx.x;
  float s0=0.f, s1=0.f, s2=0.f, s3=0.f;
  const float* arow = adj + (size_t)n*NN;
  for (int c = t; c < NN; c += 256){
    float a = arow[c];
    float4 v = *reinterpret_cast<const float4*>(cm + c*4);
    s0 = fmaf(a, v.x, s0); s1 = fmaf(a, v.y, s1);
    s2 = fmaf(a, v.z, s2); s3 = fmaf(a, v.w, s3);
  }
  red[t][0]=s0; red[t][1]=s1; red[t][2]=s2; red[t][3]=s3;
  __syncthreads();
  for (int off = 128; off > 0; off >>= 1){
    if (t < off){
      red[t][0]+=red[t+off][0]; red[t][1]+=red[t+off][1];
      red[t][2]+=red[t+off][2]; red[t][3]+=red[t+off][3];
    }
    __syncthreads();
  }
  if (t < 4) ch[n*4+t] = red[0][t];
}

// pack rank-4 weight matrices f32, interleaved per column (no precision change)
__global__ __launch_bounds__(256) void k_prep(
    const float* __restrict__ Wcw, const float* __restrict__ bcw,
    const float* __restrict__ Wgw, const float* __restrict__ bgw,
    const float* __restrict__ Wrw, const float* __restrict__ brw,
    float* __restrict__ PKW, float* __restrict__ PKB, float* __restrict__ PKR)
{
  int col = blockIdx.x*256 + threadIdx.x;
  if (col < 13824){
    float4 a = make_float4(Wcw[col], Wcw[13824+col], Wcw[27648+col], Wcw[41472+col]);
    float4 b = make_float4(Wgw[col], Wgw[13824+col], Wgw[27648+col], Wgw[41472+col]);
    *reinterpret_cast<float4*>(PKW + (size_t)col*8)     = a;
    *reinterpret_cast<float4*>(PKW + (size_t)col*8 + 4) = b;
    *reinterpret_cast<float2*>(PKB + (size_t)col*2) = make_float2(bcw[col], bgw[col]);
  }
  if (col < 3072){
    float4 r = make_float4(Wrw[col], Wrw[3072+col], Wrw[6144+col], Wrw[9216+col]);
    *reinterpret_cast<float4*>(PKR + (size_t)col*8) = r;
    PKR[(size_t)col*8 + 4] = brw[col];
  }
}

// per-layer stat reduction: stats[layer*32+j] = sum_n parts[n*32+j]
__global__ __launch_bounds__(256) void k_stats(
    int layer, const float* __restrict__ parts, float* __restrict__ stats)
{
  __shared__ float red[256];
  const int j = blockIdx.x, tid = threadIdx.x;
  float s = 0.f;
  for (int i = tid; i < NN; i += 256) s += parts[(size_t)i*32 + j];
  red[tid] = s;
  __syncthreads();
  for (int off = 128; off > 0; off >>= 1){
    if (tid < off) red[tid] += red[tid+off];
    __syncthreads();
  }
  if (tid == 0) stats[layer*32 + j] = red[0];
}

// ---------------------------------------------------------------------------
// k_layer (R6 structure): split-K A tiles, gh overlay, 3 blocks/CU.
// Weight-gen reads f32 packed (PKW/PKB/PKR): 3 vector loads per column.
// Stats: per-block partials to parts[n][32] (no atomics).
// ---------------------------------------------------------------------------
__global__ __launch_bounds__(256,3) void k_layer(
    int layer,
    __fp16* __restrict__ xbuf, float* __restrict__ skipbuf,
    const float* __restrict__ ch, const float* __restrict__ stats,
    float* __restrict__ parts,
    const float* __restrict__ input,
    const float* __restrict__ PKW, const float* __restrict__ PKB,
    const float* __restrict__ PKR,
    const float* __restrict__ Wcb, const float* __restrict__ bcb,
    const float* __restrict__ Wgb, const float* __restrict__ bgb,
    const float* __restrict__ Wrb, const float* __restrict__ brb,
    const float* __restrict__ start_w, const float* __restrict__ start_b,
    const float* __restrict__ sk0w, const float* __restrict__ sk0b,
    const float* __restrict__ skw_all, const float* __restrict__ skb_all,
    const float* __restrict__ lnw_all, const float* __restrict__ lnb_all)
{
  __shared__ __fp16 AhG[10752];      // 21504 B  (A tiles, later gh overlay)
  __shared__ __fp16 xh[7680];        // 15360 B  [t][b][c] stride 40
  __shared__ __fp16 rwh[1280];       //  2560 B
  __shared__ float skred[1024];      //  4096 B
  __shared__ float wred[128];        //   512 B
  __shared__ float ubuf[1280];       //  5120 B
  __shared__ float skwv[384];        //  1536 B
  __shared__ float skbv[32], fbias[32], gbias[32], rbv[32];
  __shared__ float muv[16], rsv[16];

  const int tid = threadIdx.x;
  const int n = blockIdx.x;

  float* swv  = ubuf;        // 64   (layer 0)
  float* sbv  = ubuf + 64;   // 32
  float* s0wv = ubuf + 96;   // 768
  float* s0bv = ubuf + 864;  // 32
  float* xin  = ubuf + 896;  // 384 = 16 b x 24
  float* lnwv = ubuf;        // 384  (layer > 0), [c*12+t]
  float* lnbv = ubuf + 384;  // 384

  const float c0v = ch[n*4+0], c1v = ch[n*4+1], c2v = ch[n*4+2], c3v = ch[n*4+3];

  // ---- phase 0 constants ----
  for (int i = tid; i < 32; i += 256) skbv[i] = skb_all[layer*32+i];
  for (int i = tid; i < 384; i += 256) skwv[i] = skw_all[layer*384+i];
  if (layer == 0){
    for (int i = tid; i < 64; i += 256) swv[i] = start_w[i];
    for (int i = tid; i < 32; i += 256){ sbv[i] = start_b[i]; s0bv[i] = sk0b[i]; }
    for (int i = tid; i < 768; i += 256) s0wv[i] = sk0w[i];
    for (int i = tid; i < 384; i += 256){
      int bb = i/24, r = i%24, d = r/12, t = r%12;
      xin[i] = input[(((size_t)bb*2 + d)*NN + n)*13 + t];
    }
  } else {
    for (int i = tid; i < 384; i += 256){
      int c = i/12, t = i%12;
      size_t o = (((size_t)(layer-1)*32 + c)*NN + n)*12 + t;
      lnwv[i] = lnw_all[o]; lnbv[i] = lnb_all[o];
    }
    if (tid < 16){
      float S1 = stats[(layer-1)*32 + tid];
      float S2 = stats[(layer-1)*32 + 16 + tid];
      const float M = 768000.0f;
      float mu = S1 / M;
      muv[tid] = mu;
      rsv[tid] = rsqrtf(S2/M - mu*mu + 1e-5f);
    }
  }

  // ---- phase 1: weight gen from f32 packed (3 vector loads per col) ----
  for (int i = tid; i < 4608; i += 256){
    int o   = i / 576;
    int rem = i - o*576;
    int c   = rem / 18;
    int u   = rem - c*18;
    int s   = (u >= 2) + (u >= 5) + (u >= 11);
    int lo  = (s == 0) ? 0 : ((s == 1) ? 2 : ((s == 2) ? 5 : 11));
    int jj  = u - lo;
    int col = layer*4608 + i;
    float4 pwf = *reinterpret_cast<const float4*>(PKW + (size_t)col*8);
    float4 pwg = *reinterpret_cast<const float4*>(PKW + (size_t)col*8 + 4);
    float2 pb  = *reinterpret_cast<const float2*>(PKB + (size_t)col*2);
    float wf = fmaf(c0v, pwf.x, fmaf(c1v, pwf.y,
               fmaf(c2v, pwf.z, fmaf(c3v, pwf.w, pb.x))));
    float wg = fmaf(c0v, pwg.x, fmaf(c1v, pwg.y,
               fmaf(c2v, pwg.z, fmaf(c3v, pwg.w, pb.y))));
    int base = (s >= 2) ? 3328 : 0;
    int strd = (s >= 2) ? 232 : 104;
    int r    = ((s & 1) << 3) + o;
    int k    = jj*32 + c;
    AhG[base + r*strd + k]        = (__fp16)wf;
    AhG[base + (16 + r)*strd + k] = (__fp16)wg;
  }
  // zero padding slots (s=0 jj=2; s=2 jj=6)
  for (int i = tid; i < 1024; i += 256){
    int grp = i >> 8, rem = i & 255, r = rem >> 5, c = rem & 31;
    int base = (grp < 2) ? 0 : 3328;
    int strd = (grp < 2) ? 104 : 232;
    int off  = (grp < 2) ? 64 : 192;
    int gofs = (grp & 1) ? 16*strd : 0;
    AhG[base + gofs + r*strd + off + c] = (__fp16)0.f;
  }
  for (int i = tid; i < 1024; i += 256){
    int col = layer*1024 + i;
    float4 pr = *reinterpret_cast<const float4*>(PKR + (size_t)col*8);
    float rb = PKR[(size_t)col*8 + 4];
    float v = fmaf(c0v, pr.x, fmaf(c1v, pr.y,
              fmaf(c2v, pr.z, fmaf(c3v, pr.w, rb))));
    rwh[(i>>5)*40 + (i&31)] = (__fp16)v;
  }
  if (tid < 32){
    int oc = tid;
    int s = oc >> 3;
    int v = ((n&3)<<3) + (oc&7);               // bias reshuffle: column
    int col = layer*32 + v;
    float cb0 = ch[(s*500 + (n>>2))*4 + 0];
    float cb1 = ch[(s*500 + (n>>2))*4 + 1];
    float cb2 = ch[(s*500 + (n>>2))*4 + 2];
    float cb3 = ch[(s*500 + (n>>2))*4 + 3];
    fbias[oc] = fmaf(cb0, Wcb[col], fmaf(cb1, Wcb[96+col],
                fmaf(cb2, Wcb[192+col], fmaf(cb3, Wcb[288+col], bcb[col]))));
    gbias[oc] = fmaf(cb0, Wgb[col], fmaf(cb1, Wgb[96+col],
                fmaf(cb2, Wgb[192+col], fmaf(cb3, Wgb[288+col], bgb[col]))));
    int colr = layer*32 + oc;
    rbv[oc] = fmaf(c0v, Wrb[colr], fmaf(c1v, Wrb[96+colr],
              fmaf(c2v, Wrb[192+colr], fmaf(c3v, Wrb[288+colr], brb[colr]))));
  }
  __syncthreads();

  // ---- staging: xh[t][b][c] f16 ----
  if (tid < 192){
    int b = tid / 12, t = tid - (tid/12)*12;
    float xv[32];
    if (layer == 0){
      float xa = xin[b*24 + t], xb2 = xin[b*24 + 12 + t];
#pragma unroll
      for (int c = 0; c < 32; ++c)
        xv[c] = fmaf(swv[c*2], xa, fmaf(swv[c*2+1], xb2, sbv[c]));
    } else {
      const uint4* src = reinterpret_cast<const uint4*>(
          xbuf + (((size_t)b*NN + n)*12 + t)*32);
      uint4 u0 = src[0], u1 = src[1], u2 = src[2], u3 = src[3];
      unsigned int uu[16] = {u0.x,u0.y,u0.z,u0.w, u1.x,u1.y,u1.z,u1.w,
                             u2.x,u2.y,u2.z,u2.w, u3.x,u3.y,u3.z,u3.w};
      float mu = muv[b], rs = rsv[b];
#pragma unroll
      for (int j = 0; j < 16; ++j){
        U32H2 vv; vv.u = uu[j];
        int c = j*2;
        xv[c]   = fmaf(((float)vv.h[0]-mu)*rs, lnwv[c*12+t],     lnbv[c*12+t]);
        xv[c+1] = fmaf(((float)vv.h[1]-mu)*rs, lnwv[(c+1)*12+t], lnbv[(c+1)*12+t]);
      }
    }
    unsigned int pk[16];
#pragma unroll
    for (int j = 0; j < 16; ++j) pk[j] = pkh(xv[2*j], xv[2*j+1]);
    uint4* dst = reinterpret_cast<uint4*>(&xh[(t*16 + b)*40]);
    dst[0] = make_uint4(pk[0], pk[1], pk[2], pk[3]);
    dst[1] = make_uint4(pk[4], pk[5], pk[6], pk[7]);
    dst[2] = make_uint4(pk[8], pk[9], pk[10], pk[11]);
    dst[3] = make_uint4(pk[12],pk[13],pk[14],pk[15]);
  }
  __syncthreads();

  // ---- phase 2: load A frags, barrier (frees AhG), MFMA conv ----
  const int lane = tid & 63, w = tid >> 6;
  const int h = w & 1, nh = w >> 1;
  const int r16 = lane & 15, hi4 = lane >> 4;
  const int c0 = hi4*8;
  const int oc0 = h*16 + hi4*4;

  const __fp16* Ab = AhG + (h ? 3328 : 0);
  const int As  = h ? 232 : 104;
  const int njj = h ? 7 : 3;
  f16x8 aF[7], aG[7];
#pragma unroll 7
  for (int jj = 0; jj < 7; ++jj) if (jj < njj){
    aF[jj] = *reinterpret_cast<const f16x8*>(&Ab[r16*As + jj*32 + c0]);
    aG[jj] = *reinterpret_cast<const f16x8*>(&Ab[(16 + r16)*As + jj*32 + c0]);
  }
  f16x8 ar = *reinterpret_cast<const f16x8*>(&rwh[(h*16 + r16)*40 + c0]);
  float fb4[4], gb4[4], rb4[4];
#pragma unroll
  for (int i2 = 0; i2 < 4; ++i2){
    fb4[i2] = fbias[oc0+i2]; gb4[i2] = gbias[oc0+i2]; rb4[i2] = rbv[oc0+i2];
  }
  __syncthreads();                    // all A frags in regs -> AhG reusable
  __fp16* gh = AhG;                   // gh[t][b][c], stride 40

  float sv[4] = {0.f, 0.f, 0.f, 0.f};
#pragma unroll
  for (int q = 0; q < 6; ++q){
    int nt = nh*6 + q;
    f32x4 accf = {0.f,0.f,0.f,0.f}, accg = {0.f,0.f,0.f,0.f};
#pragma unroll 7
    for (int jj = 0; jj < 7; ++jj) if (jj < njj){
      int tp = nt + jj; if (tp >= 12) tp -= 12;
      f16x8 bf = *reinterpret_cast<const f16x8*>(&xh[(tp*16 + r16)*40 + c0]);
      accf = __builtin_amdgcn_mfma_f32_16x16x32_f16(aF[jj], bf, accf, 0, 0, 0);
      accg = __builtin_amdgcn_mfma_f32_16x16x32_f16(aG[jj], bf, accg, 0, 0, 0);
    }
    float gv4[4];
#pragma unroll
    for (int i2 = 0; i2 < 4; ++i2){
      float fv = ftanh(accf[i2] + fb4[i2]);
      float gg = fsig(accg[i2] + gb4[i2]);
      gv4[i2] = fv * gg;
      sv[i2] = fmaf(gv4[i2], skwv[(oc0+i2)*12 + nt], sv[i2]);
    }
    *reinterpret_cast<uint2*>(&gh[(nt*16 + r16)*40 + oc0]) =
        make_uint2(pkh(gv4[0], gv4[1]), pkh(gv4[2], gv4[3]));
  }
#pragma unroll
  for (int i2 = 0; i2 < 4; ++i2)
    skred[((oc0+i2)*16 + r16)*2 + nh] = sv[i2];
  __syncthreads();

  // ---- phase 3: skip finalize + residual GEMM + epilogue + stat partials ----
  for (int e = tid; e < 512; e += 256){
    int b = e >> 5, oc = e & 31;
    float sk = skred[(oc*16+b)*2] + skred[(oc*16+b)*2+1] + skbv[oc];
    size_t so = ((size_t)b*NN + n)*32 + oc;
    if (layer == 0){
      float s0 = s0bv[oc];
#pragma unroll
      for (int r = 0; r < 24; ++r) s0 = fmaf(xin[b*24+r], s0wv[oc*24+r], s0);
      skipbuf[so] = sk + s0;
    } else {
      skipbuf[so] += sk;
    }
  }
  {
    float s1 = 0.f, s2 = 0.f;
#pragma unroll
    for (int q = 0; q < 6; ++q){
      int nt = nh*6 + q;
      f16x8 bg = *reinterpret_cast<const f16x8*>(&gh[(nt*16 + r16)*40 + c0]);
      f32x4 z = {0.f,0.f,0.f,0.f};
      f32x4 acc = __builtin_amdgcn_mfma_f32_16x16x32_f16(ar, bg, z, 0, 0, 0);
      uint2 xu = *reinterpret_cast<const uint2*>(&xh[(nt*16 + r16)*40 + oc0]);
      U32H2 ua, ub; ua.u = xu.x; ub.u = xu.y;
      float o0 = acc[0] + rb4[0] + (float)ua.h[0];
      float o1 = acc[1] + rb4[1] + (float)ua.h[1];
      float o2 = acc[2] + rb4[2] + (float)ub.h[0];
      float o3 = acc[3] + rb4[3] + (float)ub.h[1];
      *reinterpret_cast<uint2*>(
          xbuf + (((size_t)r16*NN + n)*12 + nt)*32 + oc0) =
          make_uint2(pkh(o0, o1), pkh(o2, o3));
      s1 += o0 + o1 + o2 + o3;
      s2 = fmaf(o0,o0, fmaf(o1,o1, fmaf(o2,o2, fmaf(o3,o3, s2))));
    }
    s1 += __shfl_xor(s1, 16); s2 += __shfl_xor(s2, 16);
    s1 += __shfl_xor(s1, 32); s2 += __shfl_xor(s2, 32);
    if (hi4 == 0){
      wred[(w*16 + r16)*2]     = s1;
      wred[(w*16 + r16)*2 + 1] = s2;
    }
  }
  __syncthreads();
  if (tid < 16){
    float a1 = 0.f, a2 = 0.f;
    for (int w2 = 0; w2 < 4; ++w2){
      a1 += wred[(w2*16 + tid)*2];
      a2 += wred[(w2*16 + tid)*2 + 1];
    }
    parts[(size_t)n*32 + tid]      = a1;
    parts[(size_t)n*32 + 16 + tid] = a2;
  }
}

__global__ __launch_bounds__(256) void k_final(
    const __fp16* __restrict__ xbuf, const float* __restrict__ skipbuf,
    const float* __restrict__ stats,
    const float* __restrict__ lnw_all, const float* __restrict__ lnb_all,
    const float* __restrict__ skEw, const float* __restrict__ skEb,
    const float* __restrict__ e1w, const float* __restrict__ e1b,
    const float* __restrict__ e2w, const float* __restrict__ e2b,
    float* __restrict__ out)
{
  __shared__ float lnw[384], lnb[384], skE[384];
  __shared__ float e1[32*33];
  __shared__ float e1bv[32], e2v[32], skEbv[32];
  __shared__ float muv[16], rsv[16];
  __shared__ float skf[8][33];
  const int tid = threadIdx.x, n = blockIdx.x;
  for (int i = tid; i < 384; i += 256){
    int c = i/12, t = i%12;
    size_t o = (((size_t)2*32 + c)*NN + n)*12 + t;
    lnw[i] = lnw_all[o]; lnb[i] = lnb_all[o];
    skE[i] = skEw[i];
  }
  for (int i = tid; i < 1024; i += 256) e1[(i>>5)*33 + (i&31)] = e1w[i];
  if (tid < 32){ e1bv[tid] = e1b[tid]; e2v[tid] = e2w[tid]; skEbv[tid] = skEb[tid]; }
  if (tid < 16){
    float S1 = stats[64+tid], S2 = stats[80+tid];
    const float M = 768000.0f;
    float mu = S1/M; muv[tid] = mu;
    rsv[tid] = rsqrtf(S2/M - mu*mu + 1e-5f);
  }
  __syncthreads();
  const float e2b0 = e2b[0];
  for (int bo = 0; bo < 2; ++bo){
    const int g = tid >> 5, c = tid & 31, b = bo*8 + g;
    float xr[12];
#pragma unroll
    for (int t = 0; t < 12; ++t)
      xr[t] = (float)xbuf[(((size_t)b*NN + n)*12 + t)*32 + c];
    const float mu = muv[b], rs = rsv[b];
    float se = 0.0f;
#pragma unroll
    for (int t = 0; t < 12; ++t){
      float xv = fmaf((xr[t]-mu)*rs, lnw[c*12+t], lnb[c*12+t]);
      se = fmaf(xv, skE[c*12+t], se);
    }
    float sk = se + skEbv[c] + skipbuf[((size_t)b*NN+n)*32 + c];
    skf[g][c] = fmaxf(sk, 0.0f);
    __syncthreads();
    float acc = e1bv[c];
#pragma unroll
    for (int cc = 0; cc < 32; ++cc) acc = fmaf(skf[g][cc], e1[c*33+cc], acc);
    float y1 = fmaxf(acc, 0.0f);
    float part = y1 * e2v[c];
#pragma unroll
    for (int off = 16; off > 0; off >>= 1) part += __shfl_down(part, off, 32);
    if (c == 0) out[(size_t)b*NN + n] = part + e2b0;
    __syncthreads();
  }
}

extern "C" void kernel_launch(void* const* d_in, const int* in_sizes, int n_in,
                              void* d_out, int out_size, void* d_ws, size_t ws_size,
                              hipStream_t stream)
{
  (void)in_sizes; (void)n_in; (void)out_size; (void)ws_size;
  const float* input   = (const float*)d_in[0];
  const float* adj     = (const float*)d_in[1];
  const float* charac  = (const float*)d_in[2];
  const float* Wcw     = (const float*)d_in[3];
  const float* bcw     = (const float*)d_in[4];
  const float* Wcb     = (const float*)d_in[5];
  const float* bcb     = (const float*)d_in[6];
  const float* Wgw     = (const float*)d_in[7];
  const float* bgw     = (const float*)d_in[8];
  const float* Wgb     = (const float*)d_in[9];
  const float* bgb     = (const float*)d_in[10];
  const float* Wrw     = (const float*)d_in[11];
  const float* brw     = (const float*)d_in[12];
  const float* Wrb     = (const float*)d_in[13];
  const float* brb     = (const float*)d_in[14];
  const float* start_w = (const float*)d_in[15];
  const float* start_b = (const float*)d_in[16];
  const float* sk0w    = (const float*)d_in[17];
  const float* sk0b    = (const float*)d_in[18];
  const float* skw     = (const float*)d_in[19];
  const float* skb     = (const float*)d_in[20];
  const float* skEw    = (const float*)d_in[21];
  const float* skEb    = (const float*)d_in[22];
  const float* lnw     = (const float*)d_in[23];
  const float* lnb     = (const float*)d_in[24];
  const float* e1w     = (const float*)d_in[25];
  const float* e1b     = (const float*)d_in[26];
  const float* e2w     = (const float*)d_in[27];
  const float* e2b     = (const float*)d_in[28];

  float* ws     = (float*)d_ws;
  __fp16* xbuf  = (__fp16*)(ws + XOFF);
  float* skipb  = ws + SKOFF;
  float* chbuf  = ws + CHOFF;
  float* cmbuf  = ws + CMOFF;
  float* stats  = ws + STOFF;
  float* parts  = ws + PARTOFF;
  float* PKW    = ws + PKWOFF;
  float* PKB    = ws + PKBOFF;
  float* PKR    = ws + PKROFF;
  float* outp   = (float*)d_out;

  k_prep<<<54, 256, 0, stream>>>(Wcw, bcw, Wgw, bgw, Wrw, brw, PKW, PKB, PKR);
  k_charm<<<32, 256, 0, stream>>>(input, charac, cmbuf);
  k_ch<<<NN, 256, 0, stream>>>(adj, cmbuf, chbuf);
  for (int layer = 0; layer < 3; ++layer){
    k_layer<<<NN, 256, 0, stream>>>(layer, xbuf, skipb, chbuf, stats, parts, input,
        PKW, PKB, PKR, Wcb, bcb, Wgb, bgb, Wrb, brb,
        start_w, start_b, sk0w, sk0b, skw, skb, lnw, lnb);
    k_stats<<<32, 256, 0, stream>>>(layer, parts, stats);
  }
  k_final<<<NN, 256, 0, stream>>>(xbuf, skipb, stats, lnw, lnb,
      skEw, skEb, e1w, e1b, e2w, e2b, outp);
}

// Round 10
// 218.933 us; speedup vs baseline: 1.6335x; 1.0358x over previous
//
#include <hip/hip_runtime.h>

#define NN 2000
#define TT 12

// workspace layout (in floats)
#define XOFF    0          // x buffer f16: (B,N,T,C) f16 = 6,144,000 floats
#define SKOFF   6144000    // skip: (B,N,C) f32
#define CHOFF   7168000    // ch: N*4
#define CMOFF   7176000    // char_m: N*4
#define STOFF   7184000    // stats: 96
#define PARTOFF 7184100    // per-node stat partials: 2000*32
#define PKWOFF  7248100    // packed conv+gate rank weights f32 [layer][o][u][c]: 13824*8
#define PKBOFF  7358692    // packed conv+gate rank biases f32 [layer][o][u][c]: 13824*2
#define PKROFF  7386340    // packed residual rank weights f32: 3072*8
// total ~7,410,916 floats = 29.6 MB

typedef __fp16 f16x8 __attribute__((ext_vector_type(8)));
typedef float  f32x4 __attribute__((ext_vector_type(4)));

union U32H2 { unsigned int u; __fp16 h[2]; };
__device__ __forceinline__ unsigned int pkh(float a, float b){
  U32H2 v; v.h[0] = (__fp16)a; v.h[1] = (__fp16)b; return v.u;
}
__device__ __forceinline__ float fsig(float x){ return 1.0f/(1.0f + __expf(-x)); }
__device__ __forceinline__ float ftanh(float x){ return 1.0f - 2.0f/(1.0f + __expf(2.0f*x)); }

__global__ void k_charm(const float* __restrict__ input,
                        const float* __restrict__ charac,
                        float* __restrict__ cm)
{
  int idx = blockIdx.x*256 + threadIdx.x;
  if (idx >= NN*4) return;
  int n = idx >> 2, r = idx & 3;
  int mv = (int)input[TT];
  int m = ((mv % 12) + 12) % 12;
  int m0 = (m + 11) % 12, m2 = (m + 1) % 12;
  const float* base = charac + n*48;
  cm[idx] = (base[m0*4+r] + base[m*4+r] + base[m2*4+r]) * (1.0f/3.0f);
}

__global__ __launch_bounds__(256) void k_ch(const float* __restrict__ adj,
                                            const float* __restrict__ cm,
                                            float* __restrict__ ch)
{
  __shared__ float red[256][4];
  int n = blockIdx.x, t = threadIdx.x;
  float s0=0.f, s1=0.f, s2=0.f, s3=0.f;
  const float* arow = adj + (size_t)n*NN;
  for (int c = t; c < NN; c += 256){
    float a = arow[c];
    float4 v = *reinterpret_cast<const float4*>(cm + c*4);
    s0 = fmaf(a, v.x, s0); s1 = fmaf(a, v.y, s1);
    s2 = fmaf(a, v.z, s2); s3 = fmaf(a, v.w, s3);
  }
  red[t][0]=s0; red[t][1]=s1; red[t][2]=s2; red[t][3]=s3;
  __syncthreads();
  for (int off = 128; off > 0; off >>= 1){
    if (t < off){
      red[t][0]+=red[t+off][0]; red[t][1]+=red[t+off][1];
      red[t][2]+=red[t+off][2]; red[t][3]+=red[t+off][3];
    }
    __syncthreads();
  }
  if (t < 4) ch[n*4+t] = red[0][t];
}

// pack rank-4 weight matrices f32, re-laid out to [layer][o][u][c] so that
// k_layer's weight-gen is c-fastest (coalesced loads AND conflict-free LDS writes)
__global__ __launch_bounds__(256) void k_prep(
    const float* __restrict__ Wcw, const float* __restrict__ bcw,
    const float* __restrict__ Wgw, const float* __restrict__ bgw,
    const float* __restrict__ Wrw, const float* __restrict__ brw,
    float* __restrict__ PKW, float* __restrict__ PKB, float* __restrict__ PKR)
{
  int col = blockIdx.x*256 + threadIdx.x;
  if (col < 13824){
    int layer = col / 4608;
    int i     = col - layer*4608;
    int o     = i / 576;
    int rem   = i - o*576;
    int c     = rem / 18;
    int u     = rem - c*18;
    size_t j  = (size_t)layer*4608 + o*576 + u*32 + c;
    float4 a = make_float4(Wcw[col], Wcw[13824+col], Wcw[27648+col], Wcw[41472+col]);
    float4 b = make_float4(Wgw[col], Wgw[13824+col], Wgw[27648+col], Wgw[41472+col]);
    *reinterpret_cast<float4*>(PKW + j*8)     = a;
    *reinterpret_cast<float4*>(PKW + j*8 + 4) = b;
    *reinterpret_cast<float2*>(PKB + j*2) = make_float2(bcw[col], bgw[col]);
  }
  if (col < 3072){
    float4 r = make_float4(Wrw[col], Wrw[3072+col], Wrw[6144+col], Wrw[9216+col]);
    *reinterpret_cast<float4*>(PKR + (size_t)col*8) = r;
    PKR[(size_t)col*8 + 4] = brw[col];
  }
}

// per-layer stat reduction
__global__ __launch_bounds__(256) void k_stats(
    int layer, const float* __restrict__ parts, float* __restrict__ stats)
{
  __shared__ float red[256];
  const int j = blockIdx.x, tid = threadIdx.x;
  float s = 0.f;
  for (int i = tid; i < NN; i += 256) s += parts[(size_t)i*32 + j];
  red[tid] = s;
  __syncthreads();
  for (int off = 128; off > 0; off >>= 1){
    if (tid < off) red[tid] += red[tid+off];
    __syncthreads();
  }
  if (tid == 0) stats[layer*32 + j] = red[0];
}

// ---------------------------------------------------------------------------
// k_layer: R9 structure; weight-gen re-indexed c-fastest (conflict-free).
// ---------------------------------------------------------------------------
__global__ __launch_bounds__(256,3) void k_layer(
    int layer,
    __fp16* __restrict__ xbuf, float* __restrict__ skipbuf,
    const float* __restrict__ ch, const float* __restrict__ stats,
    float* __restrict__ parts,
    const float* __restrict__ input,
    const float* __restrict__ PKW, const float* __restrict__ PKB,
    const float* __restrict__ PKR,
    const float* __restrict__ Wcb, const float* __restrict__ bcb,
    const float* __restrict__ Wgb, const float* __restrict__ bgb,
    const float* __restrict__ Wrb, const float* __restrict__ brb,
    const float* __restrict__ start_w, const float* __restrict__ start_b,
    const float* __restrict__ sk0w, const float* __restrict__ sk0b,
    const float* __restrict__ skw_all, const float* __restrict__ skb_all,
    const float* __restrict__ lnw_all, const float* __restrict__ lnb_all)
{
  __shared__ __fp16 AhG[10752];      // 21504 B  (A tiles, later gh overlay)
  __shared__ __fp16 xh[7680];        // 15360 B  [t][b][c] stride 40
  __shared__ __fp16 rwh[1280];       //  2560 B
  __shared__ float skred[1024];      //  4096 B
  __shared__ float wred[128];        //   512 B
  __shared__ float ubuf[1280];       //  5120 B
  __shared__ float skwv[384];        //  1536 B
  __shared__ float skbv[32], fbias[32], gbias[32], rbv[32];
  __shared__ float muv[16], rsv[16];

  const int tid = threadIdx.x;
  const int n = blockIdx.x;

  float* swv  = ubuf;        // 64   (layer 0)
  float* sbv  = ubuf + 64;   // 32
  float* s0wv = ubuf + 96;   // 768
  float* s0bv = ubuf + 864;  // 32
  float* xin  = ubuf + 896;  // 384 = 16 b x 24
  float* lnwv = ubuf;        // 384  (layer > 0), [c*12+t]
  float* lnbv = ubuf + 384;  // 384

  const float c0v = ch[n*4+0], c1v = ch[n*4+1], c2v = ch[n*4+2], c3v = ch[n*4+3];

  // ---- phase 0 constants ----
  for (int i = tid; i < 32; i += 256) skbv[i] = skb_all[layer*32+i];
  for (int i = tid; i < 384; i += 256) skwv[i] = skw_all[layer*384+i];
  if (layer == 0){
    for (int i = tid; i < 64; i += 256) swv[i] = start_w[i];
    for (int i = tid; i < 32; i += 256){ sbv[i] = start_b[i]; s0bv[i] = sk0b[i]; }
    for (int i = tid; i < 768; i += 256) s0wv[i] = sk0w[i];
    for (int i = tid; i < 384; i += 256){
      int bb = i/24, r = i%24, d = r/12, t = r%12;
      xin[i] = input[(((size_t)bb*2 + d)*NN + n)*13 + t];
    }
  } else {
    for (int i = tid; i < 384; i += 256){
      int c = i/12, t = i%12;
      size_t o = (((size_t)(layer-1)*32 + c)*NN + n)*12 + t;
      lnwv[i] = lnw_all[o]; lnbv[i] = lnb_all[o];
    }
    if (tid < 16){
      float S1 = stats[(layer-1)*32 + tid];
      float S2 = stats[(layer-1)*32 + 16 + tid];
      const float M = 768000.0f;
      float mu = S1 / M;
      muv[tid] = mu;
      rsv[tid] = rsqrtf(S2/M - mu*mu + 1e-5f);
    }
  }

  // ---- phase 1: weight gen, c-fastest (coalesced loads, conflict-free LDS) ----
  {
    const int cc = tid & 31;
    int g2 = tid >> 5;                       // (o,u) group, advances by 8
    const float* pkwL = PKW + (size_t)layer*4608*8;
    const float* pkbL = PKB + (size_t)layer*4608*2;
#pragma unroll
    for (int it = 0; it < 18; ++it, g2 += 8){
      int o  = g2 / 18;
      int u  = g2 - o*18;
      int s  = (u >= 2) + (u >= 5) + (u >= 11);
      int lo = (s == 0) ? 0 : ((s == 1) ? 2 : ((s == 2) ? 5 : 11));
      int jj = u - lo;
      size_t j = (size_t)g2*32 + cc;
      float4 pwf = *reinterpret_cast<const float4*>(pkwL + j*8);
      float4 pwg = *reinterpret_cast<const float4*>(pkwL + j*8 + 4);
      float2 pb  = *reinterpret_cast<const float2*>(pkbL + j*2);
      float wf = fmaf(c0v, pwf.x, fmaf(c1v, pwf.y,
                 fmaf(c2v, pwf.z, fmaf(c3v, pwf.w, pb.x))));
      float wg = fmaf(c0v, pwg.x, fmaf(c1v, pwg.y,
                 fmaf(c2v, pwg.z, fmaf(c3v, pwg.w, pb.y))));
      int base = (s >= 2) ? 3328 : 0;
      int strd = (s >= 2) ? 232 : 104;
      int r    = ((s & 1) << 3) + o;
      int k    = jj*32 + cc;
      AhG[base + r*strd + k]        = (__fp16)wf;
      AhG[base + (16 + r)*strd + k] = (__fp16)wg;
    }
  }
  // zero padding slots (s=0 jj=2; s=2 jj=6)
  for (int i = tid; i < 1024; i += 256){
    int grp = i >> 8, rem = i & 255, r = rem >> 5, c = rem & 31;
    int base = (grp < 2) ? 0 : 3328;
    int strd = (grp < 2) ? 104 : 232;
    int off  = (grp < 2) ? 64 : 192;
    int gofs = (grp & 1) ? 16*strd : 0;
    AhG[base + gofs + r*strd + off + c] = (__fp16)0.f;
  }
  for (int i = tid; i < 1024; i += 256){
    int col = layer*1024 + i;
    float4 pr = *reinterpret_cast<const float4*>(PKR + (size_t)col*8);
    float rb = PKR[(size_t)col*8 + 4];
    float v = fmaf(c0v, pr.x, fmaf(c1v, pr.y,
              fmaf(c2v, pr.z, fmaf(c3v, pr.w, rb))));
    rwh[(i>>5)*40 + (i&31)] = (__fp16)v;
  }
  if (tid < 32){
    int oc = tid;
    int s = oc >> 3;
    int v = ((n&3)<<3) + (oc&7);               // bias reshuffle: column
    int col = layer*32 + v;
    float cb0 = ch[(s*500 + (n>>2))*4 + 0];
    float cb1 = ch[(s*500 + (n>>2))*4 + 1];
    float cb2 = ch[(s*500 + (n>>2))*4 + 2];
    float cb3 = ch[(s*500 + (n>>2))*4 + 3];
    fbias[oc] = fmaf(cb0, Wcb[col], fmaf(cb1, Wcb[96+col],
                fmaf(cb2, Wcb[192+col], fmaf(cb3, Wcb[288+col], bcb[col]))));
    gbias[oc] = fmaf(cb0, Wgb[col], fmaf(cb1, Wgb[96+col],
                fmaf(cb2, Wgb[192+col], fmaf(cb3, Wgb[288+col], bgb[col]))));
    int colr = layer*32 + oc;
    rbv[oc] = fmaf(c0v, Wrb[colr], fmaf(c1v, Wrb[96+colr],
              fmaf(c2v, Wrb[192+colr], fmaf(c3v, Wrb[288+colr], brb[colr]))));
  }
  __syncthreads();

  // ---- staging: xh[t][b][c] f16, b-fastest thread map (conflict-free writes) ----
  if (tid < 192){
    int b = tid & 15, t = tid >> 4;
    float xv[32];
    if (layer == 0){
      float xa = xin[b*24 + t], xb2 = xin[b*24 + 12 + t];
#pragma unroll
      for (int c = 0; c < 32; ++c)
        xv[c] = fmaf(swv[c*2], xa, fmaf(swv[c*2+1], xb2, sbv[c]));
    } else {
      const uint4* src = reinterpret_cast<const uint4*>(
          xbuf + (((size_t)b*NN + n)*12 + t)*32);
      uint4 u0 = src[0], u1 = src[1], u2 = src[2], u3 = src[3];
      unsigned int uu[16] = {u0.x,u0.y,u0.z,u0.w, u1.x,u1.y,u1.z,u1.w,
                             u2.x,u2.y,u2.z,u2.w, u3.x,u3.y,u3.z,u3.w};
      float mu = muv[b], rs = rsv[b];
#pragma unroll
      for (int j = 0; j < 16; ++j){
        U32H2 vv; vv.u = uu[j];
        int c = j*2;
        xv[c]   = fmaf(((float)vv.h[0]-mu)*rs, lnwv[c*12+t],     lnbv[c*12+t]);
        xv[c+1] = fmaf(((float)vv.h[1]-mu)*rs, lnwv[(c+1)*12+t], lnbv[(c+1)*12+t]);
      }
    }
    unsigned int pk[16];
#pragma unroll
    for (int j = 0; j < 16; ++j) pk[j] = pkh(xv[2*j], xv[2*j+1]);
    uint4* dst = reinterpret_cast<uint4*>(&xh[(t*16 + b)*40]);
    dst[0] = make_uint4(pk[0], pk[1], pk[2], pk[3]);
    dst[1] = make_uint4(pk[4], pk[5], pk[6], pk[7]);
    dst[2] = make_uint4(pk[8], pk[9], pk[10], pk[11]);
    dst[3] = make_uint4(pk[12],pk[13],pk[14],pk[15]);
  }
  __syncthreads();

  // ---- phase 2: load A frags, barrier (frees AhG), MFMA conv ----
  const int lane = tid & 63, w = tid >> 6;
  const int h = w & 1, nh = w >> 1;
  const int r16 = lane & 15, hi4 = lane >> 4;
  const int c0 = hi4*8;
  const int oc0 = h*16 + hi4*4;

  const __fp16* Ab = AhG + (h ? 3328 : 0);
  const int As  = h ? 232 : 104;
  const int njj = h ? 7 : 3;
  f16x8 aF[7], aG[7];
#pragma unroll 7
  for (int jj = 0; jj < 7; ++jj) if (jj < njj){
    aF[jj] = *reinterpret_cast<const f16x8*>(&Ab[r16*As + jj*32 + c0]);
    aG[jj] = *reinterpret_cast<const f16x8*>(&Ab[(16 + r16)*As + jj*32 + c0]);
  }
  f16x8 ar = *reinterpret_cast<const f16x8*>(&rwh[(h*16 + r16)*40 + c0]);
  float fb4[4], gb4[4], rb4[4];
#pragma unroll
  for (int i2 = 0; i2 < 4; ++i2){
    fb4[i2] = fbias[oc0+i2]; gb4[i2] = gbias[oc0+i2]; rb4[i2] = rbv[oc0+i2];
  }
  __syncthreads();                    // all A frags in regs -> AhG reusable
  __fp16* gh = AhG;                   // gh[t][b][c], stride 40

  float sv[4] = {0.f, 0.f, 0.f, 0.f};
#pragma unroll
  for (int q = 0; q < 6; ++q){
    int nt = nh*6 + q;
    f32x4 accf = {0.f,0.f,0.f,0.f}, accg = {0.f,0.f,0.f,0.f};
#pragma unroll 7
    for (int jj = 0; jj < 7; ++jj) if (jj < njj){
      int tp = nt + jj; if (tp >= 12) tp -= 12;
      f16x8 bf = *reinterpret_cast<const f16x8*>(&xh[(tp*16 + r16)*40 + c0]);
      accf = __builtin_amdgcn_mfma_f32_16x16x32_f16(aF[jj], bf, accf, 0, 0, 0);
      accg = __builtin_amdgcn_mfma_f32_16x16x32_f16(aG[jj], bf, accg, 0, 0, 0);
    }
    float gv4[4];
#pragma unroll
    for (int i2 = 0; i2 < 4; ++i2){
      float fv = ftanh(accf[i2] + fb4[i2]);
      float gg = fsig(accg[i2] + gb4[i2]);
      gv4[i2] = fv * gg;
      sv[i2] = fmaf(gv4[i2], skwv[(oc0+i2)*12 + nt], sv[i2]);
    }
    *reinterpret_cast<uint2*>(&gh[(nt*16 + r16)*40 + oc0]) =
        make_uint2(pkh(gv4[0], gv4[1]), pkh(gv4[2], gv4[3]));
  }
#pragma unroll
  for (int i2 = 0; i2 < 4; ++i2)
    skred[((oc0+i2)*16 + r16)*2 + nh] = sv[i2];
  __syncthreads();

  // ---- phase 3: skip finalize + residual GEMM + epilogue + stat partials ----
  for (int e = tid; e < 512; e += 256){
    int b = e >> 5, oc = e & 31;
    float sk = skred[(oc*16+b)*2] + skred[(oc*16+b)*2+1] + skbv[oc];
    size_t so = ((size_t)b*NN + n)*32 + oc;
    if (layer == 0){
      float s0 = s0bv[oc];
#pragma unroll
      for (int r = 0; r < 24; ++r) s0 = fmaf(xin[b*24+r], s0wv[oc*24+r], s0);
      skipbuf[so] = sk + s0;
    } else {
      skipbuf[so] += sk;
    }
  }
  {
    float s1 = 0.f, s2 = 0.f;
#pragma unroll
    for (int q = 0; q < 6; ++q){
      int nt = nh*6 + q;
      f16x8 bg = *reinterpret_cast<const f16x8*>(&gh[(nt*16 + r16)*40 + c0]);
      f32x4 z = {0.f,0.f,0.f,0.f};
      f32x4 acc = __builtin_amdgcn_mfma_f32_16x16x32_f16(ar, bg, z, 0, 0, 0);
      uint2 xu = *reinterpret_cast<const uint2*>(&xh[(nt*16 + r16)*40 + oc0]);
      U32H2 ua, ub; ua.u = xu.x; ub.u = xu.y;
      float o0 = acc[0] + rb4[0] + (float)ua.h[0];
      float o1 = acc[1] + rb4[1] + (float)ua.h[1];
      float o2 = acc[2] + rb4[2] + (float)ub.h[0];
      float o3 = acc[3] + rb4[3] + (float)ub.h[1];
      *reinterpret_cast<uint2*>(
          xbuf + (((size_t)r16*NN + n)*12 + nt)*32 + oc0) =
          make_uint2(pkh(o0, o1), pkh(o2, o3));
      s1 += o0 + o1 + o2 + o3;
      s2 = fmaf(o0,o0, fmaf(o1,o1, fmaf(o2,o2, fmaf(o3,o3, s2))));
    }
    s1 += __shfl_xor(s1, 16); s2 += __shfl_xor(s2, 16);
    s1 += __shfl_xor(s1, 32); s2 += __shfl_xor(s2, 32);
    if (hi4 == 0){
      wred[(w*16 + r16)*2]     = s1;
      wred[(w*16 + r16)*2 + 1] = s2;
    }
  }
  __syncthreads();
  if (tid < 16){
    float a1 = 0.f, a2 = 0.f;
    for (int w2 = 0; w2 < 4; ++w2){
      a1 += wred[(w2*16 + tid)*2];
      a2 += wred[(w2*16 + tid)*2 + 1];
    }
    parts[(size_t)n*32 + tid]      = a1;
    parts[(size_t)n*32 + 16 + tid] = a2;
  }
}

__global__ __launch_bounds__(256) void k_final(
    const __fp16* __restrict__ xbuf, const float* __restrict__ skipbuf,
    const float* __restrict__ stats,
    const float* __restrict__ lnw_all, const float* __restrict__ lnb_all,
    const float* __restrict__ skEw, const float* __restrict__ skEb,
    const float* __restrict__ e1w, const float* __restrict__ e1b,
    const float* __restrict__ e2w, const float* __restrict__ e2b,
    float* __restrict__ out)
{
  __shared__ float lnw[384], lnb[384], skE[384];
  __shared__ float e1[32*33];
  __shared__ float e1bv[32], e2v[32], skEbv[32];
  __shared__ float muv[16], rsv[16];
  __shared__ float skf[8][33];
  const int tid = threadIdx.x, n = blockIdx.x;
  for (int i = tid; i < 384; i += 256){
    int c = i/12, t = i%12;
    size_t o = (((size_t)2*32 + c)*NN + n)*12 + t;
    lnw[i] = lnw_all[o]; lnb[i] = lnb_all[o];
    skE[i] = skEw[i];
  }
  for (int i = tid; i < 1024; i += 256) e1[(i>>5)*33 + (i&31)] = e1w[i];
  if (tid < 32){ e1bv[tid] = e1b[tid]; e2v[tid] = e2w[tid]; skEbv[tid] = skEb[tid]; }
  if (tid < 16){
    float S1 = stats[64+tid], S2 = stats[80+tid];
    const float M = 768000.0f;
    float mu = S1/M; muv[tid] = mu;
    rsv[tid] = rsqrtf(S2/M - mu*mu + 1e-5f);
  }
  __syncthreads();
  const float e2b0 = e2b[0];
  for (int bo = 0; bo < 2; ++bo){
    const int g = tid >> 5, c = tid & 31, b = bo*8 + g;
    float xr[12];
#pragma unroll
    for (int t = 0; t < 12; ++t)
      xr[t] = (float)xbuf[(((size_t)b*NN + n)*12 + t)*32 + c];
    const float mu = muv[b], rs = rsv[b];
    float se = 0.0f;
#pragma unroll
    for (int t = 0; t < 12; ++t){
      float xv = fmaf((xr[t]-mu)*rs, lnw[c*12+t], lnb[c*12+t]);
      se = fmaf(xv, skE[c*12+t], se);
    }
    float sk = se + skEbv[c] + skipbuf[((size_t)b*NN+n)*32 + c];
    skf[g][c] = fmaxf(sk, 0.0f);
    __syncthreads();
    float acc = e1bv[c];
#pragma unroll
    for (int cc = 0; cc < 32; ++cc) acc = fmaf(skf[g][cc], e1[c*33+cc], acc);
    float y1 = fmaxf(acc, 0.0f);
    float part = y1 * e2v[c];
#pragma unroll
    for (int off = 16; off > 0; off >>= 1) part += __shfl_down(part, off, 32);
    if (c == 0) out[(size_t)b*NN + n] = part + e2b0;
    __syncthreads();
  }
}

extern "C" void kernel_launch(void* const* d_in, const int* in_sizes, int n_in,
                              void* d_out, int out_size, void* d_ws, size_t ws_size,
                              hipStream_t stream)
{
  (void)in_sizes; (void)n_in; (void)out_size; (void)ws_size;
  const float* input   = (const float*)d_in[0];
  const float* adj     = (const float*)d_in[1];
  const float* charac  = (const float*)d_in[2];
  const float* Wcw     = (const float*)d_in[3];
  const float* bcw     = (const float*)d_in[4];
  const float* Wcb     = (const float*)d_in[5];
  const float* bcb     = (const float*)d_in[6];
  const float* Wgw     = (const float*)d_in[7];
  const float* bgw     = (const float*)d_in[8];
  const float* Wgb     = (const float*)d_in[9];
  const float* bgb     = (const float*)d_in[10];
  const float* Wrw     = (const float*)d_in[11];
  const float* brw     = (const float*)d_in[12];
  const float* Wrb     = (const float*)d_in[13];
  const float* brb     = (const float*)d_in[14];
  const float* start_w = (const float*)d_in[15];
  const float* start_b = (const float*)d_in[16];
  const float* sk0w    = (const float*)d_in[17];
  const float* sk0b    = (const float*)d_in[18];
  const float* skw     = (const float*)d_in[19];
  const float* skb     = (const float*)d_in[20];
  const float* skEw    = (const float*)d_in[21];
  const float* skEb    = (const float*)d_in[22];
  const float* lnw     = (const float*)d_in[23];
  const float* lnb     = (const float*)d_in[24];
  const float* e1w     = (const float*)d_in[25];
  const float* e1b     = (const float*)d_in[26];
  const float* e2w     = (const float*)d_in[27];
  const float* e2b     = (const float*)d_in[28];

  float* ws     = (float*)d_ws;
  __fp16* xbuf  = (__fp16*)(ws + XOFF);
  float* skipb  = ws + SKOFF;
  float* chbuf  = ws + CHOFF;
  float* cmbuf  = ws + CMOFF;
  float* stats  = ws + STOFF;
  float* parts  = ws + PARTOFF;
  float* PKW    = ws + PKWOFF;
  float* PKB    = ws + PKBOFF;
  float* PKR    = ws + PKROFF;
  float* outp   = (float*)d_out;

  k_prep<<<54, 256, 0, stream>>>(Wcw, bcw, Wgw, bgw, Wrw, brw, PKW, PKB, PKR);
  k_charm<<<32, 256, 0, stream>>>(input, charac, cmbuf);
  k_ch<<<NN, 256, 0, stream>>>(adj, cmbuf, chbuf);
  for (int layer = 0; layer < 3; ++layer){
    k_layer<<<NN, 256, 0, stream>>>(layer, xbuf, skipb, chbuf, stats, parts, input,
        PKW, PKB, PKR, Wcb, bcb, Wgb, bgb, Wrb, brb,
        start_w, start_b, sk0w, sk0b, skw, skb, lnw, lnb);
    k_stats<<<32, 256, 0, stream>>>(layer, parts, stats);
  }
  k_final<<<NN, 256, 0, stream>>>(xbuf, skipb, stats, lnw, lnb,
      skEw, skEb, e1w, e1b, e2w, e2b, outp);
}